// Round 3
// baseline (341.978 us; speedup 1.0000x reference)
//
#include <hip/hip_runtime.h>

// Problem constants (from reference)
constexpr int B = 4, N = 1024, M = 64, H = 32, W = 32;
constexpr float EXPAND = 1.2f;
constexpr float TWO_SIG2 = 2.0f * 1.6f * 1.6f;   // 5.12
constexpr float GAUSS_THR = 0.6f;
constexpr float GAUSS_3D_THR = 0.5f;             // == GAUSS_DEPTH_THR, masks identical
constexpr int HW = H * W;                         // 1024
constexpr size_t S = (size_t)B * N * HW;          // per-channel stride = 4,194,304 elems
constexpr int BN = B * N;                         // 4096
constexpr int CHUNK = 32;                         // bn per block
constexpr int NCHUNK = BN / CHUNK;                // 128
constexpr int NCC = 20;                           // flat channel count

// Native clang vector type (HIP float4 rejected by nontemporal builtin)
typedef float vfloat4 __attribute__((ext_vector_type(4)));

// Restructure rationale: the old kernel had every wave store 20 channels at
// exactly 2^24-byte stride (identical addr bits [0:23]) -> all 20 bursts
// alias the same HBM channel/bank set, thrashing 20 DRAM rows per wave.
// Now each block owns ONE flat channel x 32-bn slab and writes it as a dense
// sequential stream -- the same pattern the 6.3 TB/s fill kernel uses.

enum Kind { K_CLS, K_CLSW, K_RX2, K_RY2, K_W2, K_RX3, K_RY3, K_W3, K_AUX3 };

// Flat channel table (reference return order):
//  0 cls | 1 cls_w | 2-3 reg_2d | 4-5 reg_2d_w | 6-7 reg_3d | 8-9 reg_3d_w
// 10 depth | 11 depth_w | 12-14 dim | 15-17 dim_w | 18 rot | 19 rot_w
__constant__ int d_kind[NCC] = {K_CLS, K_CLSW, K_RX2, K_RY2, K_W2, K_W2,
                                K_RX3, K_RY3, K_W3, K_W3, K_AUX3, K_W3,
                                K_AUX3, K_AUX3, K_AUX3, K_W3, K_W3, K_W3,
                                K_AUX3, K_W3};
__constant__ int d_base[NCC] = {0, 1, 2, 2, 4, 4, 6, 6, 8, 8,
                                10, 11, 12, 12, 12, 15, 15, 15, 18, 19}; // in S units
__constant__ int d_hwof[NCC] = {0, 0, 0, 1, 0, 1, 0, 1, 0, 1,
                                0, 0, 0, 1, 2, 0, 1, 2, 0, 0};           // in HW units
__constant__ int d_nch[NCC]  = {1, 1, 2, 2, 2, 2, 2, 2, 2, 2,
                                1, 1, 3, 3, 3, 3, 3, 3, 1, 1};           // per-bn stride /HW
__constant__ int d_aux[NCC]  = {7, 7, 7, 7, 7, 7, 7, 7, 7, 7,
                                12, 7, 7, 8, 9, 7, 7, 7, 13, 7};         // gt_boxes field

template <int KIND>
__device__ __forceinline__ void run_loop(int bn0, int nch, int w0, float gy,
                                         const float* p_kx, const float* p_ky,
                                         const float* p_val, const float* p_has,
                                         const float* p_aux, float* outc)
{
#pragma unroll 8
    for (int i = 0; i < CHUNK; ++i) {
        const int bn   = bn0 + i;
        const float kx = p_kx[i], ky = p_ky[i];          // LDS broadcast reads
        const float vf = p_val[i], hf = p_has[i], ax = p_aux[i];
        const float dy   = gy + 0.5f - ky;
        const float dy2  = dy * dy;
        const float offy = ky - gy;
        vfloat4 v;
#pragma unroll
        for (int j = 0; j < 4; ++j) {
            const float gx = (float)(w0 + j);
            float r;
            if constexpr (KIND == K_CLSW) {
                r = hf;
            } else {
                // bit-identical score expression to the verified kernel
                const float dx = gx + 0.5f - kx;
                const float s  = expf(-((dx * dx + dy2) / TWO_SIG2));
                if constexpr (KIND == K_CLS)  r = (hf != 0.0f) ? s : -1.0f;
                if constexpr (KIND == K_RX2)  r = (kx - gx) * ((s >= GAUSS_THR)    ? vf : 0.0f);
                if constexpr (KIND == K_RY2)  r = offy      * ((s >= GAUSS_THR)    ? vf : 0.0f);
                if constexpr (KIND == K_W2)   r =             ((s >= GAUSS_THR)    ? vf : 0.0f);
                if constexpr (KIND == K_RX3)  r = (kx - gx) * ((s >= GAUSS_3D_THR) ? vf : 0.0f);
                if constexpr (KIND == K_RY3)  r = offy      * ((s >= GAUSS_3D_THR) ? vf : 0.0f);
                if constexpr (KIND == K_W3)   r =             ((s >= GAUSS_3D_THR) ? vf : 0.0f);
                if constexpr (KIND == K_AUX3) r = ax        * ((s >= GAUSS_3D_THR) ? vf : 0.0f);
            }
            v[j] = r;
        }
        __builtin_nontemporal_store(
            v, reinterpret_cast<vfloat4*>(outc + (size_t)bn * nch * HW));
    }
}

__global__ __launch_bounds__(256)
void rcnn3d_label_kernel(const float* __restrict__ boxes,      // (B,N,4)
                         const float* __restrict__ gt_boxes,   // (B,M,14)
                         const int*   __restrict__ pos_flag,   // (B,N)
                         const int*   __restrict__ gt_id,      // (B,N)
                         float* __restrict__ out)
{
    const int bid   = blockIdx.x;
    const int cc    = bid / NCHUNK;     // channel-major grid ordering
    const int chunk = bid % NCHUNK;
    const int bn0   = chunk * CHUNK;
    const int tid   = threadIdx.x;

    const int kind = d_kind[cc];
    const int auxi = d_aux[cc];
    const int nch  = d_nch[cc];
    const size_t cbase = (size_t)d_base[cc] * S + (size_t)d_hwof[cc] * HW;

    // ---- per-bn params into LDS (threads 0..31), broadcast-read later ----
    __shared__ float p_kx[CHUNK], p_ky[CHUNK], p_val[CHUNK], p_has[CHUNK], p_aux[CHUNK];
    if (tid < CHUNK) {
        const int bn = bn0 + tid;
        const int b  = bn >> 10;                       // N = 1024
        const float4 bx = *reinterpret_cast<const float4*>(boxes + (size_t)bn * 4);
        const int   gi  = gt_id[bn];
        const float* g  = gt_boxes + ((size_t)b * M + gi) * 14;

        // replicate reference float-op order exactly
        const float cx = 0.5f * (bx.x + bx.z);
        const float cy = 0.5f * (bx.y + bx.w);
        const float hw = 0.5f * (bx.z - bx.x) * EXPAND;
        const float hh = 0.5f * (bx.w - bx.y) * EXPAND;
        const float ex1 = cx - hw, ey1 = cy - hh;
        const float ex2 = cx + hw, ey2 = cy + hh;
        const float sx = (float)W / (ex2 - ex1 + 1.0f);
        const float sy = (float)H / (ey2 - ey1 + 1.0f);
        const float kx = (g[4] - ex1) * sx;
        const float ky = (g[5] - ey1) * sy;
        const bool valid = (g[6] != 0.0f) && (pos_flag[bn] > 0);

        // analytic any(m2): separable max at the clamped nearest cell center,
        // computed with the bit-identical expf expression -> exact decision
        const float nxf = fminf(fmaxf(floorf(kx), 0.0f), 31.0f);
        const float nyf = fminf(fmaxf(floorf(ky), 0.0f), 31.0f);
        const float dxn = nxf + 0.5f - kx;
        const float dyn = nyf + 0.5f - ky;
        const float dyn2 = dyn * dyn;
        const float smax = expf(-((dxn * dxn + dyn2) / TWO_SIG2));
        const bool  has  = valid && (smax >= GAUSS_THR);

        p_kx[tid]  = kx;
        p_ky[tid]  = ky;
        p_val[tid] = valid ? 1.0f : 0.0f;
        p_has[tid] = has ? 1.0f : 0.0f;
        p_aux[tid] = g[auxi];
    }
    __syncthreads();

    // ---- dense sequential writer: 1 float4 per thread per bn ----
    const int h  = tid >> 3;            // (tid*4)/32
    const int w0 = (tid & 7) * 4;
    const float gy = (float)h;
    float* outc = out + cbase + (size_t)tid * 4;

    switch (kind) {
        case K_CLS:  run_loop<K_CLS >(bn0, nch, w0, gy, p_kx, p_ky, p_val, p_has, p_aux, outc); break;
        case K_CLSW: run_loop<K_CLSW>(bn0, nch, w0, gy, p_kx, p_ky, p_val, p_has, p_aux, outc); break;
        case K_RX2:  run_loop<K_RX2 >(bn0, nch, w0, gy, p_kx, p_ky, p_val, p_has, p_aux, outc); break;
        case K_RY2:  run_loop<K_RY2 >(bn0, nch, w0, gy, p_kx, p_ky, p_val, p_has, p_aux, outc); break;
        case K_W2:   run_loop<K_W2  >(bn0, nch, w0, gy, p_kx, p_ky, p_val, p_has, p_aux, outc); break;
        case K_RX3:  run_loop<K_RX3 >(bn0, nch, w0, gy, p_kx, p_ky, p_val, p_has, p_aux, outc); break;
        case K_RY3:  run_loop<K_RY3 >(bn0, nch, w0, gy, p_kx, p_ky, p_val, p_has, p_aux, outc); break;
        case K_W3:   run_loop<K_W3  >(bn0, nch, w0, gy, p_kx, p_ky, p_val, p_has, p_aux, outc); break;
        default:     run_loop<K_AUX3>(bn0, nch, w0, gy, p_kx, p_ky, p_val, p_has, p_aux, outc); break;
    }
}

extern "C" void kernel_launch(void* const* d_in, const int* in_sizes, int n_in,
                              void* d_out, int out_size, void* d_ws, size_t ws_size,
                              hipStream_t stream) {
    const float* boxes    = (const float*)d_in[0];
    const float* gt_boxes = (const float*)d_in[1];
    const int*   pos_flag = (const int*)d_in[2];
    const int*   gt_id    = (const int*)d_in[3];
    float*       out      = (float*)d_out;

    rcnn3d_label_kernel<<<dim3(NCC * NCHUNK), dim3(256), 0, stream>>>(
        boxes, gt_boxes, pos_flag, gt_id, out);
}